// Round 11
// baseline (333.716 us; speedup 1.0000x reference)
//
#include <hip/hip_runtime.h>

// GraphSNN: per-node MLP (13->16->8->8, relu each layer) -> segment_sum over
// dag ids (20k dags) -> per-dag MLP (8->16->8->8, relu each layer) -> sum.
// Output: [num_dags*8] dag_summ ++ [8] global_summ, fp32.
//
// Round 11: deterministic counting-sort by dag-partition, fused into K1.
//   K0a hist:  per-wave 5-bucket ballot histogram of node_to_dag
//   K0b scan:  exclusive scan of cnt[b][wave] (5 blocks, 3-phase) + totals
//   K1  mlp:   r9-validated tile MLP; writes result row to BINNED position
//              sbin[base[b]+offs[b][w]+rank] (coalesced, no atomics)
//   K2  accum: dense per-partition streaming (all lanes active,
//              unconditional loads) -> stride-9 LDS acc -> flush partials
//   K3  finish: validated (DPP 4000 / NCHUNK 51 = its original geometry)

#define TILE   256    // nodes per K1 block (4 waves)
#define DPP    4000   // dags per partition; acc = 4000*9*4 = 144,000 B
#define NCHUNK 51     // accum blocks per partition; 5*51 = 255 blocks
#define NTHR2  1024

// LDS weight layout (float offsets)
#define OW0 0
#define OB0 208
#define OW1 224
#define OB1 352
#define OW2 360
#define OB2 424

// ---------------------------------------------------------------- K0a
extern "C" __global__ void __launch_bounds__(256) gsnn_hist(
    const int* __restrict__ node_to_dag,
    unsigned*  __restrict__ cnt,          // [npart][nwaves]
    int n_nodes, int nwaves, int npart)
{
    const int gid  = blockIdx.x * 256 + threadIdx.x;
    const int lane = threadIdx.x & 63;
    const int w    = gid >> 6;
    if (w >= nwaves) return;
    const int d = (gid < n_nodes) ? node_to_dag[gid] : -1;
    const int b = (d >= 0) ? (d / DPP) : -1;
    for (int bi = 0; bi < npart; ++bi) {
        const unsigned long long m = __ballot(b == bi);
        if (lane == 0) cnt[(size_t)bi * nwaves + w] = (unsigned)__popcll(m);
    }
}

// ---------------------------------------------------------------- K0b
// one block per bucket: 3-phase scan (serial segments + one LDS block-scan)
extern "C" __global__ void __launch_bounds__(1024) gsnn_scan(
    unsigned* __restrict__ cnt,           // in: counts, out: exclusive offs
    unsigned* __restrict__ totals,        // [npart]
    int nwaves)
{
    __shared__ unsigned ts[1024];
    const int tid = threadIdx.x;
    unsigned* row = cnt + (size_t)blockIdx.x * nwaves;

    const int  seg = (nwaves + 1023) / 1024;
    const long s0  = (long)tid * seg;
    const long s1  = min((long)(tid + 1) * seg, (long)nwaves);

    unsigned sum = 0;
    for (long i = s0; i < s1; ++i) sum += row[i];
    ts[tid] = sum;
    __syncthreads();

    for (int off = 1; off < 1024; off <<= 1) {
        unsigned t = 0;
        if (tid >= off) t = ts[tid - off];
        __syncthreads();
        if (tid >= off) ts[tid] += t;
        __syncthreads();
    }
    const unsigned excl = ts[tid] - sum;   // exclusive prefix of this segment
    if (tid == 1023) totals[blockIdx.x] = ts[1023];

    unsigned run = excl;
    for (long i = s0; i < s1; ++i) { const unsigned x = row[i]; row[i] = run; run += x; }
}

// ---------------------------------------------------------------- K1
extern "C" __global__ void __launch_bounds__(256) gsnn_node_mlp_bin(
    const float* __restrict__ inputs,
    const int*   __restrict__ node_to_dag,
    const float* __restrict__ w0, const float* __restrict__ b0,
    const float* __restrict__ w1, const float* __restrict__ b1,
    const float* __restrict__ w2, const float* __restrict__ b2,
    const unsigned* __restrict__ offs,     // [npart][nwaves] exclusive
    const unsigned* __restrict__ totals,   // [npart]
    float*          __restrict__ sbin,     // [n_nodes][8] binned rows
    unsigned short* __restrict__ dbin,     // [n_nodes] drow
    int n_nodes, int nwaves, int npart)
{
    __shared__ float xs[TILE * 13];   // 13,312 B
    __shared__ float wl[432];         //  1,728 B

    const int tid = threadIdx.x;

    for (int i = tid; i < 432; i += 256) {
        float v;
        if      (i < 208) v = w0[i];
        else if (i < 224) v = b0[i - 208];
        else if (i < 352) v = w1[i - 224];
        else if (i < 360) v = b1[i - 352];
        else if (i < 424) v = w2[i - 360];
        else              v = b2[i - 424];
        wl[i] = v;
    }

    const long long base   = (long long)blockIdx.x * TILE;
    const int       nvalid = (int)min((long long)TILE, (long long)n_nodes - base);

    // ---- stage tile: fully coalesced ----
    if (nvalid == TILE) {
        const float4* g4 = (const float4*)(inputs + base * 13);
        float4*       l4 = (float4*)xs;
        #pragma unroll
        for (int j = 0; j < 4; ++j) {
            const int i = tid + j * 256;
            if (i < 832) l4[i] = g4[i];
        }
    } else {
        for (int i = tid; i < nvalid * 13; i += 256)
            xs[i] = inputs[base * 13 + i];
    }
    __syncthreads();

    if (tid >= nvalid) return;

    float x[13];
    #pragma unroll
    for (int k = 0; k < 13; ++k) x[k] = xs[tid * 13 + k];

    const float4* w0v = (const float4*)(wl + OW0);
    const float4* b0v = (const float4*)(wl + OB0);
    const float4* w1v = (const float4*)(wl + OW1);
    const float4* b1v = (const float4*)(wl + OB1);
    const float4* w2v = (const float4*)(wl + OW2);
    const float4* b2v = (const float4*)(wl + OB2);

    float h0[16];
    #pragma unroll
    for (int j4 = 0; j4 < 4; ++j4) {
        const float4 b = b0v[j4];
        h0[j4*4+0]=b.x; h0[j4*4+1]=b.y; h0[j4*4+2]=b.z; h0[j4*4+3]=b.w;
    }
    #pragma unroll
    for (int k = 0; k < 13; ++k) {
        const float xv = x[k];
        #pragma unroll
        for (int j4 = 0; j4 < 4; ++j4) {
            const float4 w = w0v[k*4 + j4];
            h0[j4*4+0] = fmaf(xv, w.x, h0[j4*4+0]);
            h0[j4*4+1] = fmaf(xv, w.y, h0[j4*4+1]);
            h0[j4*4+2] = fmaf(xv, w.z, h0[j4*4+2]);
            h0[j4*4+3] = fmaf(xv, w.w, h0[j4*4+3]);
        }
    }
    #pragma unroll
    for (int i = 0; i < 16; ++i) h0[i] = fmaxf(h0[i], 0.f);

    float h1[8];
    #pragma unroll
    for (int j4 = 0; j4 < 2; ++j4) {
        const float4 b = b1v[j4];
        h1[j4*4+0]=b.x; h1[j4*4+1]=b.y; h1[j4*4+2]=b.z; h1[j4*4+3]=b.w;
    }
    #pragma unroll
    for (int k = 0; k < 16; ++k) {
        const float xv = h0[k];
        #pragma unroll
        for (int j4 = 0; j4 < 2; ++j4) {
            const float4 w = w1v[k*2 + j4];
            h1[j4*4+0] = fmaf(xv, w.x, h1[j4*4+0]);
            h1[j4*4+1] = fmaf(xv, w.y, h1[j4*4+1]);
            h1[j4*4+2] = fmaf(xv, w.z, h1[j4*4+2]);
            h1[j4*4+3] = fmaf(xv, w.w, h1[j4*4+3]);
        }
    }
    #pragma unroll
    for (int i = 0; i < 8; ++i) h1[i] = fmaxf(h1[i], 0.f);

    float h2[8];
    #pragma unroll
    for (int j4 = 0; j4 < 2; ++j4) {
        const float4 b = b2v[j4];
        h2[j4*4+0]=b.x; h2[j4*4+1]=b.y; h2[j4*4+2]=b.z; h2[j4*4+3]=b.w;
    }
    #pragma unroll
    for (int k = 0; k < 8; ++k) {
        const float xv = h1[k];
        #pragma unroll
        for (int j4 = 0; j4 < 2; ++j4) {
            const float4 w = w2v[k*2 + j4];
            h2[j4*4+0] = fmaf(xv, w.x, h2[j4*4+0]);
            h2[j4*4+1] = fmaf(xv, w.y, h2[j4*4+1]);
            h2[j4*4+2] = fmaf(xv, w.z, h2[j4*4+2]);
            h2[j4*4+3] = fmaf(xv, w.w, h2[j4*4+3]);
        }
    }
    #pragma unroll
    for (int i = 0; i < 8; ++i) h2[i] = fmaxf(h2[i], 0.f);

    // ---- binned write: pos = base[b] + offs[b][w] + rank ----
    const long long n    = base + tid;
    const int       d    = node_to_dag[n];
    const int       b    = d / DPP;
    const int       drow = d - b * DPP;
    const int       w    = (int)(n >> 6);
    const int       lane = tid & 63;
    const unsigned long long ltmask = (1ULL << lane) - 1ULL;

    unsigned gbase_b = 0;
    for (int bi = 0; bi < npart; ++bi)
        if (bi < b) gbase_b += totals[bi];

    for (int bi = 0; bi < npart; ++bi) {
        const unsigned long long m = __ballot(b == bi);
        if (b == bi) {
            const unsigned off = offs[(size_t)bi * nwaves + w];
            const unsigned pos = gbase_b + off + (unsigned)__popcll(m & ltmask);
            float4 o0, o1;
            o0.x=h2[0]; o0.y=h2[1]; o0.z=h2[2]; o0.w=h2[3];
            o1.x=h2[4]; o1.y=h2[5]; o1.z=h2[6]; o1.w=h2[7];
            float4* o = (float4*)(sbin + (size_t)pos * 8);
            o[0] = o0; o[1] = o1;
            dbin[pos] = (unsigned short)drow;
        }
    }
}

// ---------------------------------------------------------------- K2
extern "C" __global__ void __launch_bounds__(NTHR2) gsnn_accum(
    const float*          __restrict__ sbin,
    const unsigned short* __restrict__ dbin,
    const unsigned*       __restrict__ totals,
    float*                __restrict__ partials,   // [npart*NCHUNK][DPP*8]
    int npart)
{
    __shared__ float acc[DPP * 9];        // 144,000 B (stride-9 rows)

    const int tid = threadIdx.x;
    const int p   = blockIdx.x / NCHUNK;
    const int c   = blockIdx.x % NCHUNK;

    for (int i = tid; i < DPP * 9; i += NTHR2) acc[i] = 0.f;
    __syncthreads();

    size_t rbase = 0;
    for (int bi = 0; bi < npart; ++bi)
        if (bi < p) rbase += totals[bi];
    const unsigned rcnt = totals[p];

    const size_t r0 = rbase + (size_t)((unsigned long long)rcnt * c / NCHUNK);
    const size_t r1 = rbase + (size_t)((unsigned long long)rcnt * (c + 1) / NCHUNK);

    for (size_t i = r0 + tid; i < r1; i += NTHR2) {
        const float4* r = (const float4*)(sbin + i * 8);
        const float4 a = r[0], bb = r[1];
        const int drow = (int)dbin[i];
        float* dst = acc + (size_t)drow * 9;
        atomicAdd(dst + 0, a.x);  atomicAdd(dst + 1, a.y);
        atomicAdd(dst + 2, a.z);  atomicAdd(dst + 3, a.w);
        atomicAdd(dst + 4, bb.x); atomicAdd(dst + 5, bb.y);
        atomicAdd(dst + 6, bb.z); atomicAdd(dst + 7, bb.w);
    }
    __syncthreads();

    // flush: un-pad stride-9 -> dense [DPP*8] (K3's validated layout)
    float4* out4 = (float4*)(partials + (size_t)blockIdx.x * (DPP * 8));
    for (int f = tid; f < DPP * 2; f += NTHR2) {
        const int row = f >> 1, j0 = (f & 1) << 2;
        const float* a = acc + row * 9 + j0;
        float4 vv; vv.x = a[0]; vv.y = a[1]; vv.z = a[2]; vv.w = a[3];
        out4[f] = vv;
    }
}

// ---------------------------------------------------------------- K3
// (validated structure at DPP 4000 / NCHUNK 51 — its original geometry)
extern "C" __global__ void __launch_bounds__(256) gsnn_dag_finish(
    const float* __restrict__ partials,
    const float* __restrict__ w0, const float* __restrict__ b0,
    const float* __restrict__ w1, const float* __restrict__ b1,
    const float* __restrict__ w2, const float* __restrict__ b2,
    float* __restrict__ dag_summ,
    float* __restrict__ global_out,
    int num_dags)
{
    __shared__ float4 w0s[32];   // [8][16] as [k*4 + j4]
    __shared__ float4 b0s[4];
    __shared__ float4 w1s[32];   // [16][8] as [k*2 + j4]
    __shared__ float4 b1s[2];
    __shared__ float4 w2s[16];   // [8][8]  as [k*2 + j4]
    __shared__ float4 b2s[2];
    __shared__ float  gsum_s[8];

    const int tid = threadIdx.x;
    {
        float* p;
        p = (float*)w0s; for (int i = tid; i < 128; i += 256) p[i] = w0[i];
        p = (float*)w1s; for (int i = tid; i < 128; i += 256) p[i] = w1[i];
        p = (float*)w2s; if (tid < 64) p[tid] = w2[tid];
        p = (float*)b0s; if (tid < 16) p[tid] = b0[tid];
        p = (float*)b1s; if (tid < 8)  p[tid] = b1[tid];
        p = (float*)b2s; if (tid < 8)  p[tid] = b2[tid];
    }
    if (tid < 8) gsum_s[tid] = 0.f;
    __syncthreads();

    const int d = blockIdx.x * 256 + tid;

    float h2[8] = {0.f,0.f,0.f,0.f,0.f,0.f,0.f,0.f};
    if (d < num_dags) {
        const int p_  = d / DPP;
        const int loc = d - p_ * DPP;
        float x[8] = {0.f,0.f,0.f,0.f,0.f,0.f,0.f,0.f};
        #pragma unroll 4
        for (int cc = 0; cc < NCHUNK; ++cc) {
            const float4* r = (const float4*)(partials +
                ((size_t)(p_ * NCHUNK + cc) * DPP + loc) * 8);
            const float4 a = r[0], b = r[1];
            x[0]+=a.x; x[1]+=a.y; x[2]+=a.z; x[3]+=a.w;
            x[4]+=b.x; x[5]+=b.y; x[6]+=b.z; x[7]+=b.w;
        }
        {   // write dag_summ row
            float4 o0, o1;
            o0.x=x[0]; o0.y=x[1]; o0.z=x[2]; o0.w=x[3];
            o1.x=x[4]; o1.y=x[5]; o1.z=x[6]; o1.w=x[7];
            float4* out4 = (float4*)(dag_summ + (size_t)d * 8);
            out4[0] = o0; out4[1] = o1;
        }

        float h0[16];
        #pragma unroll
        for (int j4 = 0; j4 < 4; ++j4) {
            const float4 b = b0s[j4];
            h0[j4*4+0]=b.x; h0[j4*4+1]=b.y; h0[j4*4+2]=b.z; h0[j4*4+3]=b.w;
        }
        #pragma unroll
        for (int k = 0; k < 8; ++k) {
            #pragma unroll
            for (int j4 = 0; j4 < 4; ++j4) {
                const float4 w = w0s[k*4 + j4];
                h0[j4*4+0] = fmaf(x[k], w.x, h0[j4*4+0]);
                h0[j4*4+1] = fmaf(x[k], w.y, h0[j4*4+1]);
                h0[j4*4+2] = fmaf(x[k], w.z, h0[j4*4+2]);
                h0[j4*4+3] = fmaf(x[k], w.w, h0[j4*4+3]);
            }
        }
        #pragma unroll
        for (int i = 0; i < 16; ++i) h0[i] = fmaxf(h0[i], 0.f);

        float h1[8];
        #pragma unroll
        for (int j4 = 0; j4 < 2; ++j4) {
            const float4 b = b1s[j4];
            h1[j4*4+0]=b.x; h1[j4*4+1]=b.y; h1[j4*4+2]=b.z; h1[j4*4+3]=b.w;
        }
        #pragma unroll
        for (int k = 0; k < 16; ++k) {
            #pragma unroll
            for (int j4 = 0; j4 < 2; ++j4) {
                const float4 w = w1s[k*2 + j4];
                h1[j4*4+0] = fmaf(h0[k], w.x, h1[j4*4+0]);
                h1[j4*4+1] = fmaf(h0[k], w.y, h1[j4*4+1]);
                h1[j4*4+2] = fmaf(h0[k], w.z, h1[j4*4+2]);
                h1[j4*4+3] = fmaf(h0[k], w.w, h1[j4*4+3]);
            }
        }
        #pragma unroll
        for (int i = 0; i < 8; ++i) h1[i] = fmaxf(h1[i], 0.f);

        #pragma unroll
        for (int j4 = 0; j4 < 2; ++j4) {
            const float4 b = b2s[j4];
            h2[j4*4+0]=b.x; h2[j4*4+1]=b.y; h2[j4*4+2]=b.z; h2[j4*4+3]=b.w;
        }
        #pragma unroll
        for (int k = 0; k < 8; ++k) {
            #pragma unroll
            for (int j4 = 0; j4 < 2; ++j4) {
                const float4 w = w2s[k*2 + j4];
                h2[j4*4+0] = fmaf(h1[k], w.x, h2[j4*4+0]);
                h2[j4*4+1] = fmaf(h1[k], w.y, h2[j4*4+1]);
                h2[j4*4+2] = fmaf(h1[k], w.z, h2[j4*4+2]);
                h2[j4*4+3] = fmaf(h1[k], w.w, h2[j4*4+3]);
            }
        }
        #pragma unroll
        for (int i = 0; i < 8; ++i) h2[i] = fmaxf(h2[i], 0.f);
    }

    #pragma unroll
    for (int j = 0; j < 8; ++j) {
        float v = h2[j];
        for (int off = 32; off > 0; off >>= 1) v += __shfl_down(v, off);
        if ((tid & 63) == 0) atomicAdd(&gsum_s[j], v);
    }
    __syncthreads();
    if (tid < 8) atomicAdd(global_out + tid, gsum_s[tid]);
}

// ---------------------------------------------------------------- fallbacks
extern "C" __global__ void __launch_bounds__(256) gsnn_node_atomic(
    const float* __restrict__ inputs,
    const int*   __restrict__ node_to_dag,
    const float* __restrict__ w0, const float* __restrict__ b0,
    const float* __restrict__ w1, const float* __restrict__ b1,
    const float* __restrict__ w2, const float* __restrict__ b2,
    float* __restrict__ dag_out,
    int n_nodes)
{
    const long long i = (long long)blockIdx.x * 256 + threadIdx.x;
    if (i >= n_nodes) return;
    float x[13];
    #pragma unroll
    for (int k = 0; k < 13; ++k) x[k] = inputs[i*13 + k];
    float h0[16];
    #pragma unroll
    for (int j = 0; j < 16; ++j) h0[j] = b0[j];
    #pragma unroll
    for (int k = 0; k < 13; ++k)
        #pragma unroll
        for (int j = 0; j < 16; ++j) h0[j] = fmaf(x[k], w0[k*16+j], h0[j]);
    #pragma unroll
    for (int j = 0; j < 16; ++j) h0[j] = fmaxf(h0[j], 0.f);
    float h1[8];
    #pragma unroll
    for (int j = 0; j < 8; ++j) h1[j] = b1[j];
    #pragma unroll
    for (int k = 0; k < 16; ++k)
        #pragma unroll
        for (int j = 0; j < 8; ++j) h1[j] = fmaf(h0[k], w1[k*8+j], h1[j]);
    #pragma unroll
    for (int j = 0; j < 8; ++j) h1[j] = fmaxf(h1[j], 0.f);
    float h2[8];
    #pragma unroll
    for (int j = 0; j < 8; ++j) h2[j] = b2[j];
    #pragma unroll
    for (int k = 0; k < 8; ++k)
        #pragma unroll
        for (int j = 0; j < 8; ++j) h2[j] = fmaf(h1[k], w2[k*8+j], h2[j]);
    float* dst = dag_out + (long long)node_to_dag[i] * 8;
    #pragma unroll
    for (int j = 0; j < 8; ++j) atomicAdd(dst + j, fmaxf(h2[j], 0.f));
}

extern "C" __global__ void __launch_bounds__(256) gsnn_dag_plain(
    const float* __restrict__ dag_summ,
    const float* __restrict__ w0, const float* __restrict__ b0,
    const float* __restrict__ w1, const float* __restrict__ b1,
    const float* __restrict__ w2, const float* __restrict__ b2,
    float* __restrict__ global_out,
    int num_dags)
{
    __shared__ float gsum_s[8];
    const int tid = threadIdx.x;
    if (tid < 8) gsum_s[tid] = 0.f;
    __syncthreads();
    const int d = blockIdx.x * 256 + tid;
    float h2[8] = {0.f,0.f,0.f,0.f,0.f,0.f,0.f,0.f};
    if (d < num_dags) {
        float x[8];
        #pragma unroll
        for (int j = 0; j < 8; ++j) x[j] = dag_summ[(size_t)d*8 + j];
        float h0[16];
        #pragma unroll
        for (int j = 0; j < 16; ++j) h0[j] = b0[j];
        #pragma unroll
        for (int k = 0; k < 8; ++k)
            #pragma unroll
            for (int j = 0; j < 16; ++j) h0[j] = fmaf(x[k], w0[k*16+j], h0[j]);
        #pragma unroll
        for (int j = 0; j < 16; ++j) h0[j] = fmaxf(h0[j], 0.f);
        float h1[8];
        #pragma unroll
        for (int j = 0; j < 8; ++j) h1[j] = b1[j];
        #pragma unroll
        for (int k = 0; k < 16; ++k)
            #pragma unroll
            for (int j = 0; j < 8; ++j) h1[j] = fmaf(h0[k], w1[k*8+j], h1[j]);
        #pragma unroll
        for (int j = 0; j < 8; ++j) h1[j] = fmaxf(h1[j], 0.f);
        #pragma unroll
        for (int j = 0; j < 8; ++j) h2[j] = b2[j];
        #pragma unroll
        for (int k = 0; k < 8; ++k)
            #pragma unroll
            for (int j = 0; j < 8; ++j) h2[j] = fmaf(h1[k], w2[k*8+j], h2[j]);
        #pragma unroll
        for (int j = 0; j < 8; ++j) h2[j] = fmaxf(h2[j], 0.f);
    }
    #pragma unroll
    for (int j = 0; j < 8; ++j) {
        float v = h2[j];
        for (int off = 32; off > 0; off >>= 1) v += __shfl_down(v, off);
        if ((tid & 63) == 0) atomicAdd(&gsum_s[j], v);
    }
    __syncthreads();
    if (tid < 8) atomicAdd(global_out + tid, gsum_s[tid]);
}

extern "C" void kernel_launch(void* const* d_in, const int* in_sizes, int n_in,
                              void* d_out, int out_size, void* d_ws, size_t ws_size,
                              hipStream_t stream) {
    const float* inputs      = (const float*)d_in[0];
    const int*   node_to_dag = (const int*)  d_in[1];
    const float* dw0 = (const float*)d_in[3];
    const float* db0 = (const float*)d_in[4];
    const float* dw1 = (const float*)d_in[5];
    const float* db1 = (const float*)d_in[6];
    const float* dw2 = (const float*)d_in[7];
    const float* db2 = (const float*)d_in[8];
    const float* gw0 = (const float*)d_in[9];
    const float* gb0 = (const float*)d_in[10];
    const float* gw1 = (const float*)d_in[11];
    const float* gb1 = (const float*)d_in[12];
    const float* gw2 = (const float*)d_in[13];
    const float* gb2 = (const float*)d_in[14];

    float* out = (float*)d_out;
    const int num_dags = (out_size - 8) / 8;
    const int n_nodes  = in_sizes[0] / 13;
    const int npart    = (num_dags + DPP - 1) / DPP;
    const int nwaves   = (n_nodes + 63) / 64;

    // ws layout: sbin | dbin | cnt/offs | totals | partials (all 16B-aligned)
    const size_t s_bytes = (size_t)n_nodes * 8 * sizeof(float);
    const size_t d_bytes = (((size_t)n_nodes * 2) + 15) & ~(size_t)15;
    const size_t c_bytes = (((size_t)npart * nwaves * 4) + 15) & ~(size_t)15;
    const size_t t_bytes = 64;
    const size_t p_bytes = (size_t)npart * NCHUNK * DPP * 8 * sizeof(float);
    const size_t need    = s_bytes + d_bytes + c_bytes + t_bytes + p_bytes;

    if (ws_size >= need && npart <= 8 && DPP <= 65536) {
        char* w = (char*)d_ws;
        float*          sbin     = (float*)w;                 w += s_bytes;
        unsigned short* dbin     = (unsigned short*)w;        w += d_bytes;
        unsigned*       cnt      = (unsigned*)w;              w += c_bytes;
        unsigned*       totals   = (unsigned*)w;              w += t_bytes;
        float*          partials = (float*)w;

        // zero only global_summ (dag_summ fully overwritten by K3)
        hipMemsetAsync(out + (size_t)num_dags * 8, 0, 8 * sizeof(float), stream);

        const int gridw = (nwaves * 64 + 255) / 256;
        gsnn_hist<<<gridw, 256, 0, stream>>>(
            node_to_dag, cnt, n_nodes, nwaves, npart);

        gsnn_scan<<<npart, 1024, 0, stream>>>(cnt, totals, nwaves);

        const int grid1 = (n_nodes + TILE - 1) / TILE;
        gsnn_node_mlp_bin<<<grid1, 256, 0, stream>>>(
            inputs, node_to_dag, dw0, db0, dw1, db1, dw2, db2,
            cnt /*now offs*/, totals, sbin, dbin, n_nodes, nwaves, npart);

        gsnn_accum<<<npart * NCHUNK, NTHR2, 0, stream>>>(
            sbin, dbin, totals, partials, npart);

        gsnn_dag_finish<<<(num_dags + 255) / 256, 256, 0, stream>>>(
            partials, gw0, gb0, gw1, gb1, gw2, gb2,
            out, out + (size_t)num_dags * 8, num_dags);
    } else {
        // fallback: validated atomic path
        hipMemsetAsync(d_out, 0, (size_t)out_size * sizeof(float), stream);
        gsnn_node_atomic<<<(n_nodes + 255) / 256, 256, 0, stream>>>(
            inputs, node_to_dag, dw0, db0, dw1, db1, dw2, db2, out, n_nodes);
        gsnn_dag_plain<<<(num_dags + 255) / 256, 256, 0, stream>>>(
            out, gw0, gb0, gw1, gb1, gw2, gb2,
            out + (size_t)num_dags * 8, num_dags);
    }
}